// Round 5
// baseline (2792.573 us; speedup 1.0000x reference)
//
#include <hip/hip_runtime.h>

#define B_    32
#define P_    197
#define D_    768
#define H_    12
#define DH    64
#define PP_   49
#define NREF  16
#define NP_   784   // NREF*PP_
#define TOPK_ 8
#define EPS_  1e-6f
#define NEGF  -1e30f
#define SCALE 0.125f   // QK_SCALE * d^-0.5

#define IT    8
#define NIT   25    // ceil(197/8)
#define CT    32
#define NCT   25    // ceil(784/32)

__device__ inline float waveReduceMax(float v) {
    #pragma unroll
    for (int off = 32; off; off >>= 1) v = fmaxf(v, __shfl_xor(v, off, 64));
    return v;
}
__device__ inline float waveReduceSum(float v) {
    #pragma unroll
    for (int off = 32; off; off >>= 1) v += __shfl_xor(v, off, 64);
    return v;
}

// ---------------- K1: full RMSNorm fp32 -> fp32
__global__ __launch_bounds__(256) void rmsnorm_kernel(
    const float* __restrict__ x, const float* __restrict__ w,
    float* __restrict__ o) {
    int row = blockIdx.x;
    int t = threadIdx.x;
    const float* xr = x + (size_t)row * D_;
    float v0 = xr[t], v1 = xr[t + 256], v2 = xr[t + 512];
    float ss = v0 * v0 + v1 * v1 + v2 * v2;
    __shared__ float red[4];
    ss = waveReduceSum(ss);
    if ((t & 63) == 0) red[t >> 6] = ss;
    __syncthreads();
    float r = rsqrtf((red[0] + red[1] + red[2] + red[3]) * (1.0f / D_) + EPS_);
    float* orow = o + (size_t)row * D_;
    orow[t]       = v0 * r * w[t];
    orow[t + 256] = v1 * r * w[t + 256];
    orow[t + 512] = v2 * r * w[t + 512];
}

// ---------------- K2: rep[h][col][dd] = vn[nref*P + idx[jp], h*64+dd]
__global__ __launch_bounds__(256) void rep_gather_kernel(
    const float* __restrict__ vn, const int* __restrict__ idx,
    float* __restrict__ rep) {
    int u = blockIdx.x * 256 + threadIdx.x;
    if (u >= H_ * NP_ * DH) return;
    int dd  = u & 63;
    int col = (u >> 6) % NP_;
    int h   = u / (NP_ * DH);
    int nref = col / PP_;
    int jp   = col - nref * PP_;
    rep[u] = vn[((size_t)(nref * P_ + idx[jp])) * D_ + h * DH + dd];
}

// ---------------- K3: sim + exact serial top-8 + softmax + v_aligned -> vsum (fp32)
__global__ __launch_bounds__(256) void sim_topk_kernel(
    const float* __restrict__ vn, const float* __restrict__ rep,
    float* __restrict__ vsum) {
    __shared__ float vrowS[IT][DH];
    __shared__ float repT[CT][DH + 1];
    __shared__ float simS[IT][NP_ + 1];
    __shared__ float thrS[IT], vmaxS[IT];

    int bid = blockIdx.x;
    int it = bid % NIT;
    int h  = (bid / NIT) % H_;
    int m  = bid / (NIT * H_);
    int i0 = it * IT;
    int t = threadIdx.x;

    for (int u = t; u < IT * DH; u += 256) {
        int r = u >> 6, dd = u & 63;
        int i = i0 + r;
        vrowS[r][dd] = (i < P_) ? vn[((size_t)(m * P_ + i)) * D_ + h * DH + dd] : 0.f;
    }

    const float* reph = rep + (size_t)h * NP_ * DH;
    int r = t >> 5, c = t & 31;

    for (int ct = 0; ct < NCT; ct++) {
        int c0 = ct * CT;
        __syncthreads();
        for (int u = t; u < CT * DH; u += 256) {
            int cc = u >> 6, dd = u & 63;
            int col = c0 + cc;
            repT[cc][dd] = (col < NP_) ? reph[(size_t)col * DH + dd] : 0.f;
        }
        __syncthreads();
        int col = c0 + c;
        if (col < NP_) {
            float s = 0.f;
            #pragma unroll
            for (int dd = 0; dd < DH; dd++)
                s += vrowS[r][dd] * repT[c][dd];
            if (m < NREF && (col / PP_) == m) s = NEGF;   // self-mask
            simS[r][col] = s;
        }
    }
    __syncthreads();

    // exact top-8 per row: serial insertion scan (thread r handles row r)
    if (t < IT) {
        float t8[TOPK_];
        #pragma unroll
        for (int z = 0; z < TOPK_; z++) t8[z] = -3.0e38f;
        for (int cc = 0; cc < NP_; cc++) {
            float s = simS[t][cc];
            if (s > t8[0]) {
                t8[0] = s;
                #pragma unroll
                for (int z = 0; z < TOPK_ - 1; z++) {
                    if (t8[z] > t8[z + 1]) { float tmp = t8[z]; t8[z] = t8[z + 1]; t8[z + 1] = tmp; }
                }
            }
        }
        thrS[t]  = t8[0];          // 8th largest (duplicate-correct value)
        vmaxS[t] = t8[TOPK_ - 1];  // row max
    }
    __syncthreads();

    int wave = t >> 6, lane = t & 63;
    for (int rr = wave; rr < IT; rr += 4) {
        int i = i0 + rr;
        if (i >= P_) continue;
        float thr = thrS[rr], vmax = vmaxS[rr];
        float lsum = 0.f;
        for (int cc = lane; cc < NP_; cc += 64) {
            float s = simS[rr][cc];
            if (s >= thr) lsum += __expf(s - vmax);
        }
        float Z = waveReduceSum(lsum);
        float invZ = 1.0f / Z;
        float acc = 0.f;
        for (int cc = 0; cc < NP_; cc++) {
            float s = simS[rr][cc];               // LDS broadcast
            if (s >= thr) {                        // wave-uniform, ~8 taken
                acc += __expf(s - vmax) * invZ * reph[(size_t)cc * DH + lane];
            }
        }
        vsum[((size_t)((m * H_ + h) * P_) + i) * DH + lane] =
            vn[((size_t)(m * P_ + i)) * D_ + h * DH + lane] + acc;
    }
}

// ---------------- K4: per-(b,h,i): scores -> softmax -> @ vsum -> fp32 out
__global__ __launch_bounds__(256) void attn_kernel(
    const float* __restrict__ qn, const float* __restrict__ kn,
    const float* __restrict__ vsum, float* __restrict__ out) {
    __shared__ float qrow[DH];
    __shared__ float prow[P_];
    __shared__ float red[4];
    __shared__ float redv[256];

    int bid = blockIdx.x;
    int i = bid % P_;
    int h = (bid / P_) % H_;
    int b = bid / (P_ * H_);
    int t = threadIdx.x;
    int wave = t >> 6, lane = t & 63;

    if (t < DH) qrow[t] = qn[((size_t)(b * P_ + i)) * D_ + h * DH + t];
    __syncthreads();

    int j = t;
    float s = NEGF;
    if (j < P_) {
        const float* krow = kn + ((size_t)(b * P_ + j)) * D_ + h * DH;
        float acc = 0.f;
        #pragma unroll
        for (int dd = 0; dd < DH; dd++) acc += qrow[dd] * krow[dd];
        s = acc * SCALE;
    }
    float mx = waveReduceMax(s);
    if (lane == 0) red[wave] = mx;
    __syncthreads();
    mx = fmaxf(fmaxf(red[0], red[1]), fmaxf(red[2], red[3]));
    float e = (j < P_) ? __expf(s - mx) : 0.f;
    float l = waveReduceSum(e);
    __syncthreads();
    if (lane == 0) red[wave] = l;
    __syncthreads();
    l = red[0] + red[1] + red[2] + red[3];
    if (j < P_) prow[j] = e / l;
    __syncthreads();

    int dd = t & 63, q4 = t >> 6;
    const float* vbase = vsum + (size_t)((b * H_ + h) * P_) * DH;
    float acc2 = 0.f;
    for (int jj = q4; jj < P_; jj += 4)
        acc2 += prow[jj] * vbase[(size_t)jj * DH + dd];
    redv[t] = acc2;
    __syncthreads();
    if (t < DH) {
        out[((size_t)(b * P_ + i)) * D_ + h * DH + t] =
            redv[t] + redv[t + 64] + redv[t + 128] + redv[t + 192];
    }
}

extern "C" void kernel_launch(void* const* d_in, const int* in_sizes, int n_in,
                              void* d_out, int out_size, void* d_ws, size_t ws_size,
                              hipStream_t stream) {
    const float* q  = (const float*)d_in[0];
    const float* k  = (const float*)d_in[1];
    const float* v  = (const float*)d_in[2];
    const float* wq = (const float*)d_in[3];
    const float* wk = (const float*)d_in[4];
    const float* wv = (const float*)d_in[5];
    const int* idx = (const int*)d_in[6];
    float* out = (float*)d_out;

    const size_t NTOK = (size_t)B_ * P_ * D_;        // 4,841,472
    const size_t REPSZ = (size_t)H_ * NP_ * DH;      // 602,112

    float* p = (float*)d_ws;
    float* qn   = p;  p += NTOK;
    float* kn   = p;  p += NTOK;
    float* vn   = p;  p += NTOK;
    float* rep  = p;  p += REPSZ;
    float* vsum = p;  p += NTOK;
    // total ~79.9 MB (round 1 precedent: no fault at this footprint)

    rmsnorm_kernel<<<B_ * P_, 256, 0, stream>>>(q, wq, qn);
    rmsnorm_kernel<<<B_ * P_, 256, 0, stream>>>(k, wk, kn);
    rmsnorm_kernel<<<B_ * P_, 256, 0, stream>>>(v, wv, vn);
    rep_gather_kernel<<<(H_ * NP_ * DH + 255) / 256, 256, 0, stream>>>(vn, idx, rep);
    sim_topk_kernel<<<B_ * H_ * NIT, 256, 0, stream>>>(vn, rep, vsum);
    attn_kernel<<<B_ * H_ * P_, 256, 0, stream>>>(qn, kn, vsum, out);
}

// Round 6
// 2024.112 us; speedup vs baseline: 1.3797x; 1.3797x over previous
//
#include <hip/hip_runtime.h>

#define B_    32
#define P_    197
#define D_    768
#define H_    12
#define DH    64
#define PP_   49
#define NREF  16
#define NP_   784   // NREF*PP_
#define TOPK_ 8
#define EPS_  1e-6f
#define NEGF  -1e30f
#define SCALE 0.125f   // QK_SCALE * d^-0.5

#define IT    8
#define NIT   25    // ceil(197/8)
#define CT    128
#define NCT   7     // ceil(784/128)
#define NJ    13    // ceil(784/64)

__device__ inline float waveReduceMax(float v) {
    #pragma unroll
    for (int off = 32; off; off >>= 1) v = fmaxf(v, __shfl_xor(v, off, 64));
    return v;
}
__device__ inline float waveReduceSum(float v) {
    #pragma unroll
    for (int off = 32; off; off >>= 1) v += __shfl_xor(v, off, 64);
    return v;
}
__device__ inline int waveReduceSumI(int v) {
    #pragma unroll
    for (int off = 32; off; off >>= 1) v += __shfl_xor(v, off, 64);
    return v;
}

// ---------------- K1: full RMSNorm fp32 -> fp32
__global__ __launch_bounds__(256) void rmsnorm_kernel(
    const float* __restrict__ x, const float* __restrict__ w,
    float* __restrict__ o) {
    int row = blockIdx.x;
    int t = threadIdx.x;
    const float* xr = x + (size_t)row * D_;
    float v0 = xr[t], v1 = xr[t + 256], v2 = xr[t + 512];
    float ss = v0 * v0 + v1 * v1 + v2 * v2;
    __shared__ float red[4];
    ss = waveReduceSum(ss);
    if ((t & 63) == 0) red[t >> 6] = ss;
    __syncthreads();
    float r = rsqrtf((red[0] + red[1] + red[2] + red[3]) * (1.0f / D_) + EPS_);
    float* orow = o + (size_t)row * D_;
    orow[t]       = v0 * r * w[t];
    orow[t + 256] = v1 * r * w[t + 256];
    orow[t + 512] = v2 * r * w[t + 512];
}

// ---------------- K2: rep[h][col][dd] = vn[nref*P + idx[jp], h*64+dd]
__global__ __launch_bounds__(256) void rep_gather_kernel(
    const float* __restrict__ vn, const int* __restrict__ idx,
    float* __restrict__ rep) {
    int u = blockIdx.x * 256 + threadIdx.x;
    if (u >= H_ * NP_ * DH) return;
    int dd  = u & 63;
    int col = (u >> 6) % NP_;
    int h   = u / (NP_ * DH);
    int nref = col / PP_;
    int jp   = col - nref * PP_;
    rep[u] = vn[((size_t)(nref * P_ + idx[jp])) * D_ + h * DH + dd];
}

// ---------------- K3: register-tiled sim GEMM + wave-parallel exact top-8 + v_aligned
__global__ __launch_bounds__(256) void sim_topk_kernel(
    const float* __restrict__ vn, const float* __restrict__ rep,
    float* __restrict__ vsum) {
    __shared__ float4 repT[CT][17];       // 34,816 B (pitch 17 f4 breaks bank stride)
    __shared__ float4 vrow4[IT][17];      //  2,176 B
    __shared__ float simS[IT][785];       // 25,120 B
    __shared__ int keptIdx[IT][32];       //  1,024 B
    __shared__ int keptCnt[IT];           // total 63,200 B

    int bid = blockIdx.x;
    int it = bid % NIT;
    int h  = (bid / NIT) % H_;
    int m  = bid / (NIT * H_);
    int i0 = it * IT;
    int t = threadIdx.x, lane = t & 63, w = t >> 6;

    // stage the 8 v-rows as float4
    if (t < IT * 16) {
        int r = t >> 4, kk = t & 15;
        int i = i0 + r;
        float4 val = make_float4(0.f, 0.f, 0.f, 0.f);
        if (i < P_) val = *(const float4*)(vn + ((size_t)(m * P_ + i)) * D_ + h * DH + kk * 4);
        vrow4[r][kk] = val;
    }
    __syncthreads();

    // hold this wave's two rows entirely in registers (128 VGPR; LDS-bound occupancy -> free)
    int row0 = w, row1 = w + 4;
    float4 vA[16], vB[16];
    #pragma unroll
    for (int kk = 0; kk < 16; kk++) { vA[kk] = vrow4[row0][kk]; vB[kk] = vrow4[row1][kk]; }

    const float* reph = rep + (size_t)h * NP_ * DH;

    for (int ct = 0; ct < NCT; ct++) {
        int c0 = ct * CT;
        if (ct) __syncthreads();                 // prev tile's repT readers done
        for (int u = t; u < CT * 16; u += 256) { // stage 128-col rep tile
            int c = u >> 4, kk = u & 15;
            int col = c0 + c;
            float4 val = make_float4(0.f, 0.f, 0.f, 0.f);
            if (col < NP_) val = *(const float4*)(reph + (size_t)col * DH + kk * 4);
            repT[c][kk] = val;
        }
        __syncthreads();
        float a00 = 0.f, a01 = 0.f, a10 = 0.f, a11 = 0.f;
        #pragma unroll
        for (int kk = 0; kk < 16; kk++) {        // 2 LDS b128 per 16 FMAs
            float4 r0 = repT[lane][kk];
            float4 r1 = repT[lane + 64][kk];
            float4 v0 = vA[kk], v1 = vB[kk];
            a00 += v0.x * r0.x + v0.y * r0.y + v0.z * r0.z + v0.w * r0.w;
            a01 += v0.x * r1.x + v0.y * r1.y + v0.z * r1.z + v0.w * r1.w;
            a10 += v1.x * r0.x + v1.y * r0.y + v1.z * r0.z + v1.w * r0.w;
            a11 += v1.x * r1.x + v1.y * r1.y + v1.z * r1.z + v1.w * r1.w;
        }
        int colA = c0 + lane, colB = colA + 64;
        if (colA < NP_) {
            bool mk = (m < NREF) && (colA / PP_ == m);   // self-mask
            simS[row0][colA] = mk ? NEGF : a00;
            simS[row1][colA] = mk ? NEGF : a10;
        }
        if (colB < NP_) {
            bool mk = (m < NREF) && (colB / PP_ == m);
            simS[row0][colB] = mk ? NEGF : a01;
            simS[row1][colB] = mk ? NEGF : a11;
        }
    }
    __syncthreads();

    // per-row: exact top-8 (duplicate-safe peel) + softmax + sparse gather
    for (int rr = w; rr < IT; rr += 4) {         // 2 rows per wave, wave-local
        int i = i0 + rr;
        if (i >= P_) continue;
        if (lane == 0) keptCnt[rr] = 0;
        float sv[NJ];                            // cache row in registers
        #pragma unroll
        for (int j = 0; j < NJ; j++) {
            int c = lane + 64 * j;
            sv[j] = (c < NP_) ? simS[rr][c] : NEGF;
        }
        float thr = 3.0e38f, vmax = NEGF;
        int remaining = TOPK_;
        for (int iter = 0; iter < TOPK_; iter++) {
            float lm = NEGF;
            #pragma unroll
            for (int j = 0; j < NJ; j++) if (sv[j] < thr) lm = fmaxf(lm, sv[j]);
            float gm = waveReduceMax(lm);
            if (iter == 0) vmax = gm;
            int lc = 0;
            #pragma unroll
            for (int j = 0; j < NJ; j++) if (sv[j] == gm) lc++;
            int gc = waveReduceSumI(lc);
            thr = gm;
            if (gc >= remaining) break;
            remaining -= gc;
        }
        float lsum = 0.f;
        #pragma unroll
        for (int j = 0; j < NJ; j++) {
            if (sv[j] >= thr) {
                lsum += __expf(sv[j] - vmax);
                int slot = atomicAdd(&keptCnt[rr], 1);
                if (slot < 32) keptIdx[rr][slot] = lane + 64 * j;
            }
        }
        float Z = waveReduceSum(lsum);
        float invZ = 1.0f / Z;
        int nk = keptCnt[rr];
        if (nk > 32) nk = 32;
        float acc = 0.f;
        for (int z = 0; z < nk; z++) {           // ~8 kept columns only
            int c = keptIdx[rr][z];
            float s = simS[rr][c];               // broadcast
            acc += __expf(s - vmax) * invZ * reph[(size_t)c * DH + lane];
        }
        vsum[((size_t)((m * H_ + h) * P_) + i) * DH + lane] =
            vn[((size_t)(m * P_ + i)) * D_ + h * DH + lane] + acc;
    }
}

// ---------------- K4: per-(b,h,i): scores -> softmax -> @ vsum -> fp32 out
__global__ __launch_bounds__(256) void attn_kernel(
    const float* __restrict__ qn, const float* __restrict__ kn,
    const float* __restrict__ vsum, float* __restrict__ out) {
    __shared__ float qrow[DH];
    __shared__ float prow[P_];
    __shared__ float red[4];
    __shared__ float redv[256];

    int bid = blockIdx.x;
    int i = bid % P_;
    int h = (bid / P_) % H_;
    int b = bid / (P_ * H_);
    int t = threadIdx.x;
    int wave = t >> 6, lane = t & 63;

    if (t < DH) qrow[t] = qn[((size_t)(b * P_ + i)) * D_ + h * DH + t];
    __syncthreads();

    int j = t;
    float s = NEGF;
    if (j < P_) {
        const float* krow = kn + ((size_t)(b * P_ + j)) * D_ + h * DH;
        float acc = 0.f;
        #pragma unroll
        for (int dd = 0; dd < DH; dd++) acc += qrow[dd] * krow[dd];
        s = acc * SCALE;
    }
    float mx = waveReduceMax(s);
    if (lane == 0) red[wave] = mx;
    __syncthreads();
    mx = fmaxf(fmaxf(red[0], red[1]), fmaxf(red[2], red[3]));
    float e = (j < P_) ? __expf(s - mx) : 0.f;
    float l = waveReduceSum(e);
    __syncthreads();
    if (lane == 0) red[wave] = l;
    __syncthreads();
    l = red[0] + red[1] + red[2] + red[3];
    if (j < P_) prow[j] = e / l;
    __syncthreads();

    int dd = t & 63, q4 = t >> 6;
    const float* vbase = vsum + (size_t)((b * H_ + h) * P_) * DH;
    float acc2 = 0.f;
    for (int jj = q4; jj < P_; jj += 4)
        acc2 += prow[jj] * vbase[(size_t)jj * DH + dd];
    redv[t] = acc2;
    __syncthreads();
    if (t < DH) {
        out[((size_t)(b * P_ + i)) * D_ + h * DH + t] =
            redv[t] + redv[t + 64] + redv[t + 128] + redv[t + 192];
    }
}

extern "C" void kernel_launch(void* const* d_in, const int* in_sizes, int n_in,
                              void* d_out, int out_size, void* d_ws, size_t ws_size,
                              hipStream_t stream) {
    const float* q  = (const float*)d_in[0];
    const float* k  = (const float*)d_in[1];
    const float* v  = (const float*)d_in[2];
    const float* wq = (const float*)d_in[3];
    const float* wk = (const float*)d_in[4];
    const float* wv = (const float*)d_in[5];
    const int* idx = (const int*)d_in[6];
    float* out = (float*)d_out;

    const size_t NTOK = (size_t)B_ * P_ * D_;        // 4,841,472
    const size_t REPSZ = (size_t)H_ * NP_ * DH;      // 602,112

    float* p = (float*)d_ws;
    float* qn   = p;  p += NTOK;
    float* kn   = p;  p += NTOK;
    float* vn   = p;  p += NTOK;
    float* rep  = p;  p += REPSZ;
    float* vsum = p;  p += NTOK;

    rmsnorm_kernel<<<B_ * P_, 256, 0, stream>>>(q, wq, qn);
    rmsnorm_kernel<<<B_ * P_, 256, 0, stream>>>(k, wk, kn);
    rmsnorm_kernel<<<B_ * P_, 256, 0, stream>>>(v, wv, vn);
    rep_gather_kernel<<<(H_ * NP_ * DH + 255) / 256, 256, 0, stream>>>(vn, idx, rep);
    sim_topk_kernel<<<B_ * H_ * NIT, 256, 0, stream>>>(vn, rep, vsum);
    attn_kernel<<<B_ * H_ * P_, 256, 0, stream>>>(qn, kn, vsum, out);
}

// Round 8
// 1389.311 us; speedup vs baseline: 2.0100x; 1.4569x over previous
//
#include <hip/hip_runtime.h>

#define B_    32
#define P_    197
#define D_    768
#define H_    12
#define DH    64
#define PP_   49
#define NREF  16
#define NP_   784   // NREF*PP_
#define TOPK_ 8
#define EPS_  1e-6f
#define NEGF  -1e30f
#define SCALE 0.125f   // QK_SCALE * d^-0.5

#define IT    8
#define NIT   25    // ceil(197/8)
#define CT    128
#define NCT   7     // ceil(784/128)
#define NJ    13    // ceil(784/64)

__device__ inline float waveReduceMax(float v) {
    #pragma unroll
    for (int off = 32; off; off >>= 1) v = fmaxf(v, __shfl_xor(v, off, 64));
    return v;
}
__device__ inline float waveReduceSum(float v) {
    #pragma unroll
    for (int off = 32; off; off >>= 1) v += __shfl_xor(v, off, 64);
    return v;
}
__device__ inline int waveReduceSumI(int v) {
    #pragma unroll
    for (int off = 32; off; off >>= 1) v += __shfl_xor(v, off, 64);
    return v;
}

// ---------------- K1: RMSNorm fp32 -> fp32
__global__ __launch_bounds__(256) void rmsnorm_kernel(
    const float* __restrict__ x, const float* __restrict__ w,
    float* __restrict__ o) {
    int row = blockIdx.x;
    int t = threadIdx.x;
    const float* xr = x + (size_t)row * D_;
    float v0 = xr[t], v1 = xr[t + 256], v2 = xr[t + 512];
    float ss = v0 * v0 + v1 * v1 + v2 * v2;
    __shared__ float red[4];
    ss = waveReduceSum(ss);
    if ((t & 63) == 0) red[t >> 6] = ss;
    __syncthreads();
    float r = rsqrtf((red[0] + red[1] + red[2] + red[3]) * (1.0f / D_) + EPS_);
    float* orow = o + (size_t)row * D_;
    orow[t]       = v0 * r * w[t];
    orow[t + 256] = v1 * r * w[t + 256];
    orow[t + 512] = v2 * r * w[t + 512];
}

// ---------------- K2: rep row-major [h][col][dd] + transposed f4 [h][kk][col]
__global__ __launch_bounds__(256) void rep_gather_kernel(
    const float* __restrict__ vn, const int* __restrict__ idx,
    float* __restrict__ repRM, float* __restrict__ repTG) {
    int u = blockIdx.x * 256 + threadIdx.x;
    if (u >= H_ * NP_ * DH) return;
    int dd  = u & 63;
    int col = (u >> 6) % NP_;
    int h   = u / (NP_ * DH);
    int nref = col / PP_;
    int jp   = col - nref * PP_;
    float val = vn[((size_t)(nref * P_ + idx[jp])) * D_ + h * DH + dd];
    repRM[u] = val;
    repTG[((size_t)(h * 16 + (dd >> 2)) * NP_ + col) * 4 + (dd & 3)] = val;
}

// ---------------- K3: conflict-free fp32 sim GEMM + top-8 + sparse v_aligned
__global__ __launch_bounds__(256) void sim_topk_kernel(
    const float* __restrict__ vn, const float* __restrict__ repRM,
    const float* __restrict__ repTG, float* __restrict__ vsum) {
    __shared__ float4 repT4[16][CT];      // 32,768 B  [kk][col] -> contiguous by lane
    __shared__ float4 vrow4[IT][16];      //  2,048 B
    __shared__ float  simS[IT][NP_ + 1];  // 25,120 B
    __shared__ int keptIdx[IT][32];
    __shared__ int keptCnt[IT];

    int bid = blockIdx.x;
    int it = bid % NIT;
    int h  = (bid / NIT) % H_;
    int m  = bid / (NIT * H_);
    int i0 = it * IT;
    int t = threadIdx.x, lane = t & 63, wid = t >> 6;

    if (t < IT * 16) {
        int r = t >> 4, kk = t & 15;
        int i = i0 + r;
        float4 val = make_float4(0.f, 0.f, 0.f, 0.f);
        if (i < P_) val = *(const float4*)(vn + ((size_t)(m * P_ + i)) * D_ + h * DH + kk * 4);
        vrow4[r][kk] = val;
    }
    const float4* repG = (const float4*)repTG + (size_t)h * 16 * NP_;  // [kk][col]
    for (int u = t; u < CT * 16; u += 256) {   // stage tile 0
        int kk = u >> 7, c = u & 127;
        repT4[kk][c] = (c < NP_) ? repG[kk * NP_ + c] : make_float4(0.f, 0.f, 0.f, 0.f);
    }
    __syncthreads();

    int row0 = wid, row1 = wid + 4;
    float4 vA[16], vB[16];
    #pragma unroll
    for (int kk = 0; kk < 16; kk++) { vA[kk] = vrow4[row0][kk]; vB[kk] = vrow4[row1][kk]; }

    float4 pf[8];
    for (int ct = 0; ct < NCT; ct++) {
        int c0 = ct * CT;
        if (ct + 1 < NCT) {                    // prefetch next tile into regs
            int c0n = c0 + CT;
            #pragma unroll
            for (int z = 0; z < 8; z++) {
                int u = t + z * 256;
                int kk = u >> 7, c = u & 127;
                int col = c0n + c;
                pf[z] = (col < NP_) ? repG[kk * NP_ + col] : make_float4(0.f, 0.f, 0.f, 0.f);
            }
        }
        float a00 = 0.f, a01 = 0.f, a10 = 0.f, a11 = 0.f;
        #pragma unroll
        for (int kk = 0; kk < 16; kk++) {
            float4 r0 = repT4[kk][lane];
            float4 r1 = repT4[kk][lane + 64];
            float4 v0 = vA[kk], v1 = vB[kk];
            a00 = fmaf(v0.x, r0.x, a00); a00 = fmaf(v0.y, r0.y, a00);
            a00 = fmaf(v0.z, r0.z, a00); a00 = fmaf(v0.w, r0.w, a00);
            a01 = fmaf(v0.x, r1.x, a01); a01 = fmaf(v0.y, r1.y, a01);
            a01 = fmaf(v0.z, r1.z, a01); a01 = fmaf(v0.w, r1.w, a01);
            a10 = fmaf(v1.x, r0.x, a10); a10 = fmaf(v1.y, r0.y, a10);
            a10 = fmaf(v1.z, r0.z, a10); a10 = fmaf(v1.w, r0.w, a10);
            a11 = fmaf(v1.x, r1.x, a11); a11 = fmaf(v1.y, r1.y, a11);
            a11 = fmaf(v1.z, r1.z, a11); a11 = fmaf(v1.w, r1.w, a11);
        }
        int colA = c0 + lane, colB = colA + 64;
        if (colA < NP_) {
            bool mk = (m < NREF) && (colA / PP_ == m);
            simS[row0][colA] = mk ? NEGF : a00;
            simS[row1][colA] = mk ? NEGF : a10;
        }
        if (colB < NP_) {
            bool mk = (m < NREF) && (colB / PP_ == m);
            simS[row0][colB] = mk ? NEGF : a01;
            simS[row1][colB] = mk ? NEGF : a11;
        }
        if (ct + 1 < NCT) {
            __syncthreads();                   // all reads of current tile done
            #pragma unroll
            for (int z = 0; z < 8; z++) {
                int u = t + z * 256;
                repT4[u >> 7][u & 127] = pf[z];
            }
            __syncthreads();                   // new tile visible
        }
    }
    // topk: wave wid owns rows wid, wid+4 — exactly the rows it wrote (no barrier needed)
    const float* reph = repRM + (size_t)h * NP_ * DH;
    for (int rr = wid; rr < IT; rr += 4) {
        int i = i0 + rr;
        if (i >= P_) continue;
        if (lane == 0) keptCnt[rr] = 0;
        float sv[NJ];
        #pragma unroll
        for (int j = 0; j < NJ; j++) {
            int c = lane + 64 * j;
            sv[j] = (c < NP_) ? simS[rr][c] : NEGF;
        }
        float thr = 3.0e38f, vmax = NEGF;
        int remaining = TOPK_;
        for (int iter = 0; iter < TOPK_; iter++) {
            float lm = NEGF;
            #pragma unroll
            for (int j = 0; j < NJ; j++) if (sv[j] < thr) lm = fmaxf(lm, sv[j]);
            float gm = waveReduceMax(lm);
            if (iter == 0) vmax = gm;
            int lc = 0;
            #pragma unroll
            for (int j = 0; j < NJ; j++) if (sv[j] == gm) lc++;
            int gc = waveReduceSumI(lc);
            thr = gm;
            if (gc >= remaining) break;
            remaining -= gc;
        }
        float lsum = 0.f;
        #pragma unroll
        for (int j = 0; j < NJ; j++) {
            if (sv[j] >= thr) {
                lsum += __expf(sv[j] - vmax);
                int slot = atomicAdd(&keptCnt[rr], 1);
                if (slot < 32) keptIdx[rr][slot] = lane + 64 * j;
            }
        }
        float Z = waveReduceSum(lsum);
        float invZ = 1.0f / Z;
        int nk = keptCnt[rr];
        if (nk > 32) nk = 32;
        float acc = 0.f;
        for (int z = 0; z < nk; z++) {
            int c = keptIdx[rr][z];
            float s = simS[rr][c];
            acc += __expf(s - vmax) * invZ * reph[(size_t)c * DH + lane];
        }
        vsum[((size_t)((m * H_ + h) * P_) + i) * DH + lane] =
            vn[((size_t)(m * P_ + i)) * D_ + h * DH + lane] + acc;
    }
}

// ---------------- K4: per-(b,h,i): scores -> softmax -> @ vsum -> fp32 out
// (exact round-6 version — proven correct)
__global__ __launch_bounds__(256) void attn_kernel(
    const float* __restrict__ qn, const float* __restrict__ kn,
    const float* __restrict__ vsum, float* __restrict__ out) {
    __shared__ float qrow[DH];
    __shared__ float prow[P_];
    __shared__ float red[4];
    __shared__ float redv[256];

    int bid = blockIdx.x;
    int i = bid % P_;
    int h = (bid / P_) % H_;
    int b = bid / (P_ * H_);
    int t = threadIdx.x;
    int wave = t >> 6, lane = t & 63;

    if (t < DH) qrow[t] = qn[((size_t)(b * P_ + i)) * D_ + h * DH + t];
    __syncthreads();

    int j = t;
    float s = NEGF;
    if (j < P_) {
        const float* krow = kn + ((size_t)(b * P_ + j)) * D_ + h * DH;
        float acc = 0.f;
        #pragma unroll
        for (int dd = 0; dd < DH; dd++) acc += qrow[dd] * krow[dd];
        s = acc * SCALE;
    }
    float mx = waveReduceMax(s);
    if (lane == 0) red[wave] = mx;
    __syncthreads();
    mx = fmaxf(fmaxf(red[0], red[1]), fmaxf(red[2], red[3]));
    float e = (j < P_) ? __expf(s - mx) : 0.f;
    float l = waveReduceSum(e);
    __syncthreads();
    if (lane == 0) red[wave] = l;
    __syncthreads();
    l = red[0] + red[1] + red[2] + red[3];
    if (j < P_) prow[j] = e / l;
    __syncthreads();

    int dd = t & 63, q4 = t >> 6;
    const float* vbase = vsum + (size_t)((b * H_ + h) * P_) * DH;
    float acc2 = 0.f;
    for (int jj = q4; jj < P_; jj += 4)
        acc2 += prow[jj] * vbase[(size_t)jj * DH + dd];
    redv[t] = acc2;
    __syncthreads();
    if (t < DH) {
        out[((size_t)(b * P_ + i)) * D_ + h * DH + t] =
            redv[t] + redv[t + 64] + redv[t + 128] + redv[t + 192];
    }
}

extern "C" void kernel_launch(void* const* d_in, const int* in_sizes, int n_in,
                              void* d_out, int out_size, void* d_ws, size_t ws_size,
                              hipStream_t stream) {
    const float* q  = (const float*)d_in[0];
    const float* k  = (const float*)d_in[1];
    const float* v  = (const float*)d_in[2];
    const float* wq = (const float*)d_in[3];
    const float* wk = (const float*)d_in[4];
    const float* wv = (const float*)d_in[5];
    const int* idx = (const int*)d_in[6];
    float* out = (float*)d_out;

    const size_t NTOK = (size_t)B_ * P_ * D_;        // 4,841,472
    const size_t REPSZ = (size_t)H_ * NP_ * DH;      // 602,112

    float* p = (float*)d_ws;
    float* qn    = p;  p += NTOK;
    float* kn    = p;  p += NTOK;
    float* vn    = p;  p += NTOK;
    float* repRM = p;  p += REPSZ;
    float* repTG = p;  p += REPSZ;
    float* vsum  = p;  p += NTOK;   // total ~82.3 MB

    rmsnorm_kernel<<<B_ * P_, 256, 0, stream>>>(q, wq, qn);
    rmsnorm_kernel<<<B_ * P_, 256, 0, stream>>>(k, wk, kn);
    rmsnorm_kernel<<<B_ * P_, 256, 0, stream>>>(v, wv, vn);
    rep_gather_kernel<<<(H_ * NP_ * DH + 255) / 256, 256, 0, stream>>>(vn, idx, repRM, repTG);
    sim_topk_kernel<<<B_ * H_ * NIT, 256, 0, stream>>>(vn, repRM, repTG, vsum);
    attn_kernel<<<B_ * H_ * P_, 256, 0, stream>>>(qn, kn, vsum, out);
}

// Round 9
// 1206.819 us; speedup vs baseline: 2.3140x; 1.1512x over previous
//
#include <hip/hip_runtime.h>

#define B_    32
#define P_    197
#define D_    768
#define H_    12
#define DH    64
#define PP_   49
#define NREF  16
#define NP_   784   // NREF*PP_
#define TOPK_ 8
#define EPS_  1e-6f
#define NEGF  -1e30f
#define SCALE 0.125f   // QK_SCALE * d^-0.5

#define IT    8
#define NIT   25    // ceil(197/8)
#define CT    128
#define NCT   7     // ceil(784/128)
#define NJ    13    // ceil(784/64)

__device__ inline float waveReduceMax(float v) {
    #pragma unroll
    for (int off = 32; off; off >>= 1) v = fmaxf(v, __shfl_xor(v, off, 64));
    return v;
}
__device__ inline float waveReduceSum(float v) {
    #pragma unroll
    for (int off = 32; off; off >>= 1) v += __shfl_xor(v, off, 64);
    return v;
}
__device__ inline int waveReduceSumI(int v) {
    #pragma unroll
    for (int off = 32; off; off >>= 1) v += __shfl_xor(v, off, 64);
    return v;
}

// ---------------- K1: RMSNorm fp32 -> fp32
__global__ __launch_bounds__(256) void rmsnorm_kernel(
    const float* __restrict__ x, const float* __restrict__ w,
    float* __restrict__ o) {
    int row = blockIdx.x;
    int t = threadIdx.x;
    const float* xr = x + (size_t)row * D_;
    float v0 = xr[t], v1 = xr[t + 256], v2 = xr[t + 512];
    float ss = v0 * v0 + v1 * v1 + v2 * v2;
    __shared__ float red[4];
    ss = waveReduceSum(ss);
    if ((t & 63) == 0) red[t >> 6] = ss;
    __syncthreads();
    float r = rsqrtf((red[0] + red[1] + red[2] + red[3]) * (1.0f / D_) + EPS_);
    float* orow = o + (size_t)row * D_;
    orow[t]       = v0 * r * w[t];
    orow[t + 256] = v1 * r * w[t + 256];
    orow[t + 512] = v2 * r * w[t + 512];
}

// ---------------- K1b: transpose kn -> knT[(b*H+h)*64+dd][j]
__global__ __launch_bounds__(256) void ktrans_kernel(
    const float* __restrict__ kn, float* __restrict__ knT) {
    __shared__ float tile[64][65];
    int bh = blockIdx.x;
    int h = bh % H_;
    int b = bh / H_;
    int t = threadIdx.x, lane = t & 63, wid = t >> 6;
    for (int j0 = 0; j0 < P_; j0 += 64) {
        __syncthreads();                       // protect previous tile reads
        for (int r = wid; r < 64; r += 4) {    // load rows j0+r, coalesced in dd
            int j = j0 + r;
            tile[r][lane] = (j < P_) ? kn[((size_t)(b * P_ + j)) * D_ + h * DH + lane] : 0.f;
        }
        __syncthreads();
        for (int r = wid; r < 64; r += 4) {    // r = dd; write coalesced in j
            int j = j0 + lane;
            if (j < P_) knT[((size_t)bh * DH + r) * P_ + j] = tile[lane][r];
        }
    }
}

// ---------------- K2: rep row-major [h][col][dd] + transposed f4 [h][kk][col]
__global__ __launch_bounds__(256) void rep_gather_kernel(
    const float* __restrict__ vn, const int* __restrict__ idx,
    float* __restrict__ repRM, float* __restrict__ repTG) {
    int u = blockIdx.x * 256 + threadIdx.x;
    if (u >= H_ * NP_ * DH) return;
    int dd  = u & 63;
    int col = (u >> 6) % NP_;
    int h   = u / (NP_ * DH);
    int nref = col / PP_;
    int jp   = col - nref * PP_;
    float val = vn[((size_t)(nref * P_ + idx[jp])) * D_ + h * DH + dd];
    repRM[u] = val;
    repTG[((size_t)(h * 16 + (dd >> 2)) * NP_ + col) * 4 + (dd & 3)] = val;
}

// ---------------- K3: conflict-free fp32 sim GEMM + top-8 + sparse v_aligned
__global__ __launch_bounds__(256) void sim_topk_kernel(
    const float* __restrict__ vn, const float* __restrict__ repRM,
    const float* __restrict__ repTG, float* __restrict__ vsum) {
    __shared__ float4 repT4[16][CT];      // [kk][col] -> lane-consecutive b128
    __shared__ float4 vrow4[IT][16];
    __shared__ float  simS[IT][NP_ + 1];
    __shared__ int keptIdx[IT][32];
    __shared__ int keptCnt[IT];

    int bid = blockIdx.x;
    int it = bid % NIT;
    int h  = (bid / NIT) % H_;
    int m  = bid / (NIT * H_);
    int i0 = it * IT;
    int t = threadIdx.x, lane = t & 63, wid = t >> 6;

    if (t < IT * 16) {
        int r = t >> 4, kk = t & 15;
        int i = i0 + r;
        float4 val = make_float4(0.f, 0.f, 0.f, 0.f);
        if (i < P_) val = *(const float4*)(vn + ((size_t)(m * P_ + i)) * D_ + h * DH + kk * 4);
        vrow4[r][kk] = val;
    }
    const float4* repG = (const float4*)repTG + (size_t)h * 16 * NP_;  // [kk][col]
    for (int u = t; u < CT * 16; u += 256) {   // stage tile 0
        int kk = u >> 7, c = u & 127;
        repT4[kk][c] = (c < NP_) ? repG[kk * NP_ + c] : make_float4(0.f, 0.f, 0.f, 0.f);
    }
    __syncthreads();

    int row0 = wid, row1 = wid + 4;
    float4 vA[16], vB[16];
    #pragma unroll
    for (int kk = 0; kk < 16; kk++) { vA[kk] = vrow4[row0][kk]; vB[kk] = vrow4[row1][kk]; }

    float4 pf[8];
    for (int ct = 0; ct < NCT; ct++) {
        int c0 = ct * CT;
        if (ct + 1 < NCT) {                    // prefetch next tile into regs
            int c0n = c0 + CT;
            #pragma unroll
            for (int z = 0; z < 8; z++) {
                int u = t + z * 256;
                int kk = u >> 7, c = u & 127;
                int col = c0n + c;
                pf[z] = (col < NP_) ? repG[kk * NP_ + col] : make_float4(0.f, 0.f, 0.f, 0.f);
            }
        }
        float a00 = 0.f, a01 = 0.f, a10 = 0.f, a11 = 0.f;
        #pragma unroll
        for (int kk = 0; kk < 16; kk++) {
            float4 r0 = repT4[kk][lane];
            float4 r1 = repT4[kk][lane + 64];
            float4 v0 = vA[kk], v1 = vB[kk];
            a00 = fmaf(v0.x, r0.x, a00); a00 = fmaf(v0.y, r0.y, a00);
            a00 = fmaf(v0.z, r0.z, a00); a00 = fmaf(v0.w, r0.w, a00);
            a01 = fmaf(v0.x, r1.x, a01); a01 = fmaf(v0.y, r1.y, a01);
            a01 = fmaf(v0.z, r1.z, a01); a01 = fmaf(v0.w, r1.w, a01);
            a10 = fmaf(v1.x, r0.x, a10); a10 = fmaf(v1.y, r0.y, a10);
            a10 = fmaf(v1.z, r0.z, a10); a10 = fmaf(v1.w, r0.w, a10);
            a11 = fmaf(v1.x, r1.x, a11); a11 = fmaf(v1.y, r1.y, a11);
            a11 = fmaf(v1.z, r1.z, a11); a11 = fmaf(v1.w, r1.w, a11);
        }
        int colA = c0 + lane, colB = colA + 64;
        if (colA < NP_) {
            bool mk = (m < NREF) && (colA / PP_ == m);
            simS[row0][colA] = mk ? NEGF : a00;
            simS[row1][colA] = mk ? NEGF : a10;
        }
        if (colB < NP_) {
            bool mk = (m < NREF) && (colB / PP_ == m);
            simS[row0][colB] = mk ? NEGF : a01;
            simS[row1][colB] = mk ? NEGF : a11;
        }
        if (ct + 1 < NCT) {
            __syncthreads();
            #pragma unroll
            for (int z = 0; z < 8; z++) {
                int u = t + z * 256;
                repT4[u >> 7][u & 127] = pf[z];
            }
            __syncthreads();
        }
    }
    // topk: wave wid owns rows wid, wid+4 — exactly the rows it wrote
    const float* reph = repRM + (size_t)h * NP_ * DH;
    for (int rr = wid; rr < IT; rr += 4) {
        int i = i0 + rr;
        if (i >= P_) continue;
        if (lane == 0) keptCnt[rr] = 0;
        float sv[NJ];
        #pragma unroll
        for (int j = 0; j < NJ; j++) {
            int c = lane + 64 * j;
            sv[j] = (c < NP_) ? simS[rr][c] : NEGF;
        }
        float thr = 3.0e38f, vmax = NEGF;
        int remaining = TOPK_;
        for (int iter = 0; iter < TOPK_; iter++) {
            float lm = NEGF;
            #pragma unroll
            for (int j = 0; j < NJ; j++) if (sv[j] < thr) lm = fmaxf(lm, sv[j]);
            float gm = waveReduceMax(lm);
            if (iter == 0) vmax = gm;
            int lc = 0;
            #pragma unroll
            for (int j = 0; j < NJ; j++) if (sv[j] == gm) lc++;
            int gc = waveReduceSumI(lc);
            thr = gm;
            if (gc >= remaining) break;
            remaining -= gc;
        }
        float lsum = 0.f;
        #pragma unroll
        for (int j = 0; j < NJ; j++) {
            if (sv[j] >= thr) {
                lsum += __expf(sv[j] - vmax);
                int slot = atomicAdd(&keptCnt[rr], 1);
                if (slot < 32) keptIdx[rr][slot] = lane + 64 * j;
            }
        }
        float Z = waveReduceSum(lsum);
        float invZ = 1.0f / Z;
        int nk = keptCnt[rr];
        if (nk > 32) nk = 32;
        float acc = 0.f;
        for (int z = 0; z < nk; z++) {
            int c = keptIdx[rr][z];
            float s = simS[rr][c];
            acc += __expf(s - vmax) * invZ * reph[(size_t)c * DH + lane];
        }
        vsum[((size_t)((m * H_ + h) * P_) + i) * DH + lane] =
            vn[((size_t)(m * P_ + i)) * D_ + h * DH + lane] + acc;
    }
}

// ---------------- K4: per-(b,h,i) attention — round-6 math, coalesced knT reads
__global__ __launch_bounds__(256) void attn_kernel(
    const float* __restrict__ qn, const float* __restrict__ knT,
    const float* __restrict__ vsum, float* __restrict__ out) {
    __shared__ float qrow[DH];
    __shared__ float prow[P_];
    __shared__ float red[4];
    __shared__ float redv[256];

    int bid = blockIdx.x;
    int i = bid % P_;
    int h = (bid / P_) % H_;
    int b = bid / (P_ * H_);
    int t = threadIdx.x;
    int wave = t >> 6, lane = t & 63;

    if (t < DH) qrow[t] = qn[((size_t)(b * P_ + i)) * D_ + h * DH + t];
    __syncthreads();

    int j = t;
    float s = NEGF;
    if (j < P_) {
        const float* kTb = knT + (size_t)(b * H_ + h) * DH * P_;
        float acc = 0.f;
        #pragma unroll
        for (int dd = 0; dd < DH; dd++) acc += qrow[dd] * kTb[dd * P_ + j];  // lane-coalesced
        s = acc * SCALE;
    }
    float mx = waveReduceMax(s);
    if (lane == 0) red[wave] = mx;
    __syncthreads();
    mx = fmaxf(fmaxf(red[0], red[1]), fmaxf(red[2], red[3]));
    float e = (j < P_) ? __expf(s - mx) : 0.f;
    float l = waveReduceSum(e);
    __syncthreads();
    if (lane == 0) red[wave] = l;
    __syncthreads();
    l = red[0] + red[1] + red[2] + red[3];
    if (j < P_) prow[j] = e / l;
    __syncthreads();

    int dd = t & 63, q4 = t >> 6;
    const float* vbase = vsum + (size_t)((b * H_ + h) * P_) * DH;
    float acc2 = 0.f;
    for (int jj = q4; jj < P_; jj += 4)
        acc2 += prow[jj] * vbase[(size_t)jj * DH + dd];
    redv[t] = acc2;
    __syncthreads();
    if (t < DH) {
        out[((size_t)(b * P_ + i)) * D_ + h * DH + t] =
            redv[t] + redv[t + 64] + redv[t + 128] + redv[t + 192];
    }
}

extern "C" void kernel_launch(void* const* d_in, const int* in_sizes, int n_in,
                              void* d_out, int out_size, void* d_ws, size_t ws_size,
                              hipStream_t stream) {
    const float* q  = (const float*)d_in[0];
    const float* k  = (const float*)d_in[1];
    const float* v  = (const float*)d_in[2];
    const float* wq = (const float*)d_in[3];
    const float* wk = (const float*)d_in[4];
    const float* wv = (const float*)d_in[5];
    const int* idx = (const int*)d_in[6];
    float* out = (float*)d_out;

    const size_t NTOK = (size_t)B_ * P_ * D_;        // 4,841,472
    const size_t REPSZ = (size_t)H_ * NP_ * DH;      // 602,112

    float* p = (float*)d_ws;
    float* qn    = p;  p += NTOK;
    float* kn    = p;  p += NTOK;
    float* knT   = p;  p += NTOK;     // replaces vn's slot; vn lives in d_out
    float* repRM = p;  p += REPSZ;
    float* repTG = p;  p += REPSZ;
    float* vsum  = p;  p += NTOK;     // total ~82.3 MB (proven footprint)
    float* vn    = out;               // d_out as scratch: fully dead before attn writes out

    rmsnorm_kernel<<<B_ * P_, 256, 0, stream>>>(q, wq, qn);
    rmsnorm_kernel<<<B_ * P_, 256, 0, stream>>>(k, wk, kn);
    rmsnorm_kernel<<<B_ * P_, 256, 0, stream>>>(v, wv, vn);
    ktrans_kernel<<<B_ * H_, 256, 0, stream>>>(kn, knT);
    rep_gather_kernel<<<(H_ * NP_ * DH + 255) / 256, 256, 0, stream>>>(vn, idx, repRM, repTG);
    sim_topk_kernel<<<B_ * H_ * NIT, 256, 0, stream>>>(vn, repRM, repTG, vsum);
    attn_kernel<<<B_ * H_ * P_, 256, 0, stream>>>(qn, knT, vsum, out);
}

// Round 10
// 725.512 us; speedup vs baseline: 3.8491x; 1.6634x over previous
//
#include <hip/hip_runtime.h>

#define B_    32
#define P_    197
#define D_    768
#define H_    12
#define DH    64
#define PP_   49
#define NREF  16
#define NP_   784   // NREF*PP_
#define TOPK_ 8
#define EPS_  1e-6f
#define NEGF  -1e30f
#define SCALE 0.125f   // QK_SCALE * d^-0.5

#define IT    8
#define NIT   25    // ceil(197/8)
#define CT    128
#define NCT   7     // ceil(784/128)
#define NJ    13    // ceil(784/64)

__device__ inline float waveReduceMax(float v) {
    #pragma unroll
    for (int off = 32; off; off >>= 1) v = fmaxf(v, __shfl_xor(v, off, 64));
    return v;
}
__device__ inline float waveReduceSum(float v) {
    #pragma unroll
    for (int off = 32; off; off >>= 1) v += __shfl_xor(v, off, 64);
    return v;
}
__device__ inline int waveReduceSumI(int v) {
    #pragma unroll
    for (int off = 32; off; off >>= 1) v += __shfl_xor(v, off, 64);
    return v;
}

// ---------------- K1: RMSNorm fp32 -> fp32
__global__ __launch_bounds__(256) void rmsnorm_kernel(
    const float* __restrict__ x, const float* __restrict__ w,
    float* __restrict__ o) {
    int row = blockIdx.x;
    int t = threadIdx.x;
    const float* xr = x + (size_t)row * D_;
    float v0 = xr[t], v1 = xr[t + 256], v2 = xr[t + 512];
    float ss = v0 * v0 + v1 * v1 + v2 * v2;
    __shared__ float red[4];
    ss = waveReduceSum(ss);
    if ((t & 63) == 0) red[t >> 6] = ss;
    __syncthreads();
    float r = rsqrtf((red[0] + red[1] + red[2] + red[3]) * (1.0f / D_) + EPS_);
    float* orow = o + (size_t)row * D_;
    orow[t]       = v0 * r * w[t];
    orow[t + 256] = v1 * r * w[t + 256];
    orow[t + 512] = v2 * r * w[t + 512];
}

// ---------------- K1b: transpose kn -> knT[(b*H+h)*64+dd][j]
__global__ __launch_bounds__(256) void ktrans_kernel(
    const float* __restrict__ kn, float* __restrict__ knT) {
    __shared__ float tile[64][65];
    int bh = blockIdx.x;
    int h = bh % H_;
    int b = bh / H_;
    int t = threadIdx.x, lane = t & 63, wid = t >> 6;
    for (int j0 = 0; j0 < P_; j0 += 64) {
        __syncthreads();
        for (int r = wid; r < 64; r += 4) {
            int j = j0 + r;
            tile[r][lane] = (j < P_) ? kn[((size_t)(b * P_ + j)) * D_ + h * DH + lane] : 0.f;
        }
        __syncthreads();
        for (int r = wid; r < 64; r += 4) {
            int j = j0 + lane;
            if (j < P_) knT[((size_t)bh * DH + r) * P_ + j] = tile[lane][r];
        }
    }
}

// ---------------- K2: rep row-major [h][col][dd] + transposed f4 [h][kk][col]
__global__ __launch_bounds__(256) void rep_gather_kernel(
    const float* __restrict__ vn, const int* __restrict__ idx,
    float* __restrict__ repRM, float* __restrict__ repTG) {
    int u = blockIdx.x * 256 + threadIdx.x;
    if (u >= H_ * NP_ * DH) return;
    int dd  = u & 63;
    int col = (u >> 6) % NP_;
    int h   = u / (NP_ * DH);
    int nref = col / PP_;
    int jp   = col - nref * PP_;
    float val = vn[((size_t)(nref * P_ + idx[jp])) * D_ + h * DH + dd];
    repRM[u] = val;
    repTG[((size_t)(h * 16 + (dd >> 2)) * NP_ + col) * 4 + (dd & 3)] = val;
}

// ---------------- K3: conflict-free fp32 sim GEMM + top-8 + sparse v_aligned
__global__ __launch_bounds__(256) void sim_topk_kernel(
    const float* __restrict__ vn, const float* __restrict__ repRM,
    const float* __restrict__ repTG, float* __restrict__ vsum) {
    __shared__ float4 repT4[16][CT];
    __shared__ float4 vrow4[IT][16];
    __shared__ float  simS[IT][NP_ + 1];
    __shared__ int keptIdx[IT][32];
    __shared__ int keptCnt[IT];

    int bid = blockIdx.x;
    int it = bid % NIT;
    int h  = (bid / NIT) % H_;
    int m  = bid / (NIT * H_);
    int i0 = it * IT;
    int t = threadIdx.x, lane = t & 63, wid = t >> 6;

    if (t < IT * 16) {
        int r = t >> 4, kk = t & 15;
        int i = i0 + r;
        float4 val = make_float4(0.f, 0.f, 0.f, 0.f);
        if (i < P_) val = *(const float4*)(vn + ((size_t)(m * P_ + i)) * D_ + h * DH + kk * 4);
        vrow4[r][kk] = val;
    }
    const float4* repG = (const float4*)repTG + (size_t)h * 16 * NP_;
    for (int u = t; u < CT * 16; u += 256) {
        int kk = u >> 7, c = u & 127;
        repT4[kk][c] = (c < NP_) ? repG[kk * NP_ + c] : make_float4(0.f, 0.f, 0.f, 0.f);
    }
    __syncthreads();

    int row0 = wid, row1 = wid + 4;
    float4 vA[16], vB[16];
    #pragma unroll
    for (int kk = 0; kk < 16; kk++) { vA[kk] = vrow4[row0][kk]; vB[kk] = vrow4[row1][kk]; }

    float4 pf[8];
    for (int ct = 0; ct < NCT; ct++) {
        int c0 = ct * CT;
        if (ct + 1 < NCT) {
            int c0n = c0 + CT;
            #pragma unroll
            for (int z = 0; z < 8; z++) {
                int u = t + z * 256;
                int kk = u >> 7, c = u & 127;
                int col = c0n + c;
                pf[z] = (col < NP_) ? repG[kk * NP_ + col] : make_float4(0.f, 0.f, 0.f, 0.f);
            }
        }
        float a00 = 0.f, a01 = 0.f, a10 = 0.f, a11 = 0.f;
        #pragma unroll
        for (int kk = 0; kk < 16; kk++) {
            float4 r0 = repT4[kk][lane];
            float4 r1 = repT4[kk][lane + 64];
            float4 v0 = vA[kk], v1 = vB[kk];
            a00 = fmaf(v0.x, r0.x, a00); a00 = fmaf(v0.y, r0.y, a00);
            a00 = fmaf(v0.z, r0.z, a00); a00 = fmaf(v0.w, r0.w, a00);
            a01 = fmaf(v0.x, r1.x, a01); a01 = fmaf(v0.y, r1.y, a01);
            a01 = fmaf(v0.z, r1.z, a01); a01 = fmaf(v0.w, r1.w, a01);
            a10 = fmaf(v1.x, r0.x, a10); a10 = fmaf(v1.y, r0.y, a10);
            a10 = fmaf(v1.z, r0.z, a10); a10 = fmaf(v1.w, r0.w, a10);
            a11 = fmaf(v1.x, r1.x, a11); a11 = fmaf(v1.y, r1.y, a11);
            a11 = fmaf(v1.z, r1.z, a11); a11 = fmaf(v1.w, r1.w, a11);
        }
        int colA = c0 + lane, colB = colA + 64;
        if (colA < NP_) {
            bool mk = (m < NREF) && (colA / PP_ == m);
            simS[row0][colA] = mk ? NEGF : a00;
            simS[row1][colA] = mk ? NEGF : a10;
        }
        if (colB < NP_) {
            bool mk = (m < NREF) && (colB / PP_ == m);
            simS[row0][colB] = mk ? NEGF : a01;
            simS[row1][colB] = mk ? NEGF : a11;
        }
        if (ct + 1 < NCT) {
            __syncthreads();
            #pragma unroll
            for (int z = 0; z < 8; z++) {
                int u = t + z * 256;
                repT4[u >> 7][u & 127] = pf[z];
            }
            __syncthreads();
        }
    }
    const float* reph = repRM + (size_t)h * NP_ * DH;
    for (int rr = wid; rr < IT; rr += 4) {
        int i = i0 + rr;
        if (i >= P_) continue;
        if (lane == 0) keptCnt[rr] = 0;
        float sv[NJ];
        #pragma unroll
        for (int j = 0; j < NJ; j++) {
            int c = lane + 64 * j;
            sv[j] = (c < NP_) ? simS[rr][c] : NEGF;
        }
        float thr = 3.0e38f, vmax = NEGF;
        int remaining = TOPK_;
        for (int iter = 0; iter < TOPK_; iter++) {
            float lm = NEGF;
            #pragma unroll
            for (int j = 0; j < NJ; j++) if (sv[j] < thr) lm = fmaxf(lm, sv[j]);
            float gm = waveReduceMax(lm);
            if (iter == 0) vmax = gm;
            int lc = 0;
            #pragma unroll
            for (int j = 0; j < NJ; j++) if (sv[j] == gm) lc++;
            int gc = waveReduceSumI(lc);
            thr = gm;
            if (gc >= remaining) break;
            remaining -= gc;
        }
        float lsum = 0.f;
        #pragma unroll
        for (int j = 0; j < NJ; j++) {
            if (sv[j] >= thr) {
                lsum += __expf(sv[j] - vmax);
                int slot = atomicAdd(&keptCnt[rr], 1);
                if (slot < 32) keptIdx[rr][slot] = lane + 64 * j;
            }
        }
        float Z = waveReduceSum(lsum);
        float invZ = 1.0f / Z;
        int nk = keptCnt[rr];
        if (nk > 32) nk = 32;
        float acc = 0.f;
        for (int z = 0; z < nk; z++) {
            int c = keptIdx[rr][z];
            float s = simS[rr][c];
            acc += __expf(s - vmax) * invZ * reph[(size_t)c * DH + lane];
        }
        vsum[((size_t)((m * H_ + h) * P_) + i) * DH + lane] =
            vn[((size_t)(m * P_ + i)) * D_ + h * DH + lane] + acc;
    }
}

// ---------------- K4: attention, 8 query rows per block (shared k/vsum loads)
__global__ __launch_bounds__(256) void attn_kernel(
    const float* __restrict__ qn, const float* __restrict__ knT,
    const float* __restrict__ vsum, float* __restrict__ out) {
    __shared__ float4 qt4[IT][16];       //  2 KB
    __shared__ float  sc[IT][256];       //  8 KB  scores, [row][j]
    __shared__ float  prowT[256][8];     //  8 KB  softmax probs, [j][row]
    __shared__ float  redvA[IT][256];    //  8 KB  PV partials

    int bid = blockIdx.x;
    int it = bid % NIT;
    int h  = (bid / NIT) % H_;
    int b  = bid / (NIT * H_);
    int i0 = it * IT;
    int t = threadIdx.x, lane = t & 63, w = t >> 6;

    // stage 8 q rows as float4
    if (t < IT * 16) {
        int r = t >> 4, z = t & 15;
        int i = i0 + r;
        float4 val = make_float4(0.f, 0.f, 0.f, 0.f);
        if (i < P_) val = *(const float4*)(qn + ((size_t)(b * P_ + i)) * D_ + h * DH + z * 4);
        qt4[r][z] = val;
    }
    __syncthreads();

    // QK: thread t = column j; one k-load feeds 8 rows
    {
        const float* kTb = knT + (size_t)(b * H_ + h) * DH * P_;
        int j = t;
        int jc = (j < P_) ? j : 0;               // clamp (masked later)
        float acc[IT];
        #pragma unroll
        for (int r = 0; r < IT; r++) acc[r] = 0.f;
        for (int z = 0; z < 16; z++) {
            const float* kp = kTb + (size_t)(4 * z) * P_ + jc;
            float k0 = kp[0 * P_], k1 = kp[1 * P_], k2 = kp[2 * P_], k3 = kp[3 * P_];
            #pragma unroll
            for (int r = 0; r < IT; r++) {
                float4 qv = qt4[r][z];           // wave-uniform b128 broadcast
                acc[r] = fmaf(qv.x, k0, fmaf(qv.y, k1, fmaf(qv.z, k2, fmaf(qv.w, k3, acc[r]))));
            }
        }
        #pragma unroll
        for (int r = 0; r < IT; r++) sc[r][j] = acc[r] * SCALE;
    }
    __syncthreads();

    // softmax: wave w handles rows w, w+4 (wave-local, proven pattern)
    for (int rr = w; rr < IT; rr += 4) {
        float s0[4];
        #pragma unroll
        for (int g = 0; g < 4; g++) {
            int j = lane + 64 * g;
            s0[g] = (j < P_) ? sc[rr][j] : NEGF;
        }
        float mx = fmaxf(fmaxf(s0[0], s0[1]), fmaxf(s0[2], s0[3]));
        mx = waveReduceMax(mx);
        float e[4], ls = 0.f;
        #pragma unroll
        for (int g = 0; g < 4; g++) {
            int j = lane + 64 * g;
            e[g] = (j < P_) ? __expf(s0[g] - mx) : 0.f;
            ls += e[g];
        }
        float Z = waveReduceSum(ls);
        float invZ = 1.0f / Z;
        #pragma unroll
        for (int g = 0; g < 4; g++) prowT[lane + 64 * g][rr] = e[g] * invZ;
    }
    __syncthreads();

    // PV: one vsum load feeds 8 rows via prowT broadcasts
    {
        int dd = t & 63, q4 = t >> 6;
        const float* vb = vsum + (size_t)((b * H_ + h) * P_) * DH;
        float acc[IT];
        #pragma unroll
        for (int r = 0; r < IT; r++) acc[r] = 0.f;
        for (int jj = q4; jj < P_; jj += 4) {
            float vv = vb[(size_t)jj * DH + dd];
            float4 p0 = *(const float4*)&prowT[jj][0];   // wave-uniform broadcasts
            float4 p1 = *(const float4*)&prowT[jj][4];
            acc[0] = fmaf(p0.x, vv, acc[0]);
            acc[1] = fmaf(p0.y, vv, acc[1]);
            acc[2] = fmaf(p0.z, vv, acc[2]);
            acc[3] = fmaf(p0.w, vv, acc[3]);
            acc[4] = fmaf(p1.x, vv, acc[4]);
            acc[5] = fmaf(p1.y, vv, acc[5]);
            acc[6] = fmaf(p1.z, vv, acc[6]);
            acc[7] = fmaf(p1.w, vv, acc[7]);
        }
        #pragma unroll
        for (int r = 0; r < IT; r++) redvA[r][q4 * 64 + dd] = acc[r];
    }
    __syncthreads();
    if (t < DH) {
        #pragma unroll
        for (int r = 0; r < IT; r++) {
            int i = i0 + r;
            if (i < P_) {
                float o = redvA[r][t] + redvA[r][64 + t] + redvA[r][128 + t] + redvA[r][192 + t];
                out[((size_t)(b * P_ + i)) * D_ + h * DH + t] = o;
            }
        }
    }
}

extern "C" void kernel_launch(void* const* d_in, const int* in_sizes, int n_in,
                              void* d_out, int out_size, void* d_ws, size_t ws_size,
                              hipStream_t stream) {
    const float* q  = (const float*)d_in[0];
    const float* k  = (const float*)d_in[1];
    const float* v  = (const float*)d_in[2];
    const float* wq = (const float*)d_in[3];
    const float* wk = (const float*)d_in[4];
    const float* wv = (const float*)d_in[5];
    const int* idx = (const int*)d_in[6];
    float* out = (float*)d_out;

    const size_t NTOK = (size_t)B_ * P_ * D_;        // 4,841,472
    const size_t REPSZ = (size_t)H_ * NP_ * DH;      // 602,112

    float* p = (float*)d_ws;
    float* qn    = p;  p += NTOK;
    float* kn    = p;  p += NTOK;
    float* knT   = p;  p += NTOK;
    float* repRM = p;  p += REPSZ;
    float* repTG = p;  p += REPSZ;
    float* vsum  = p;  p += NTOK;     // total ~82.3 MB (proven footprint)
    float* vn    = out;               // d_out as scratch: dead before attn writes out

    rmsnorm_kernel<<<B_ * P_, 256, 0, stream>>>(q, wq, qn);
    rmsnorm_kernel<<<B_ * P_, 256, 0, stream>>>(k, wk, kn);
    rmsnorm_kernel<<<B_ * P_, 256, 0, stream>>>(v, wv, vn);
    ktrans_kernel<<<B_ * H_, 256, 0, stream>>>(kn, knT);
    rep_gather_kernel<<<(H_ * NP_ * DH + 255) / 256, 256, 0, stream>>>(vn, idx, repRM, repTG);
    sim_topk_kernel<<<B_ * H_ * NIT, 256, 0, stream>>>(vn, repRM, repTG, vsum);
    attn_kernel<<<B_ * H_ * NIT, 256, 0, stream>>>(qn, knT, vsum, out);
}